// Round 1
// baseline (527.026 us; speedup 1.0000x reference)
//
#include <hip/hip_runtime.h>

namespace {
constexpr int CH = 6;
constexpr int H  = 1024;
constexpr int W  = 1024;
constexpr float P_BURN  = 0.58f;
constexpr float W_WIND  = 0.045f;
constexpr float W_SLOPE = 0.078f;
constexpr float C45     = 0.70710678118654752f;   // sqrt(2)/2
constexpr float DEG2RAD = 0.017453292519943295f;  // pi/180

// Load 6 contiguous values [j0-1 .. j0+4] of one row, zero outside the image.
__device__ __forceinline__ void load6(const float* __restrict__ plane, int row,
                                      int j0, float v[6]) {
    if ((unsigned)row >= (unsigned)H) {
        v[0] = v[1] = v[2] = v[3] = v[4] = v[5] = 0.f;
        return;
    }
    const float* r = plane + (size_t)row * W;
    const float4 m = *reinterpret_cast<const float4*>(r + j0);  // 16B aligned
    v[0] = (j0 > 0)     ? r[j0 - 1] : 0.f;
    v[1] = m.x; v[2] = m.y; v[3] = m.z; v[4] = m.w;
    v[5] = (j0 + 4 < W) ? r[j0 + 4] : 0.f;
}
}  // namespace

__global__ __launch_bounds__(256)
void fire_step(const float* __restrict__ x, float* __restrict__ out, int B) {
    const int W4  = W / 4;
    const int gid = blockIdx.x * 256 + threadIdx.x;
    const int j0  = (gid % W4) * 4;
    const int rest = gid / W4;
    const int i = rest % H;
    const int b = rest / H;
    if (b >= B) return;

    const size_t plane = (size_t)H * W;
    const float* base_b = x + (size_t)b * CH * plane;
    const float* elev  = base_b + 0 * plane;
    const float* wsp   = base_b + 1 * plane;
    const float* wdp   = base_b + 2 * plane;
    const float* hump  = base_b + 3 * plane;
    const float* ndvip = base_b + 4 * plane;
    const float* fsp   = base_b + 5 * plane;

    float em[6], ec[6], ep[6];   // elev rows i-1, i, i+1
    load6(elev, i - 1, j0, em);
    load6(elev, i,     j0, ec);
    load6(elev, i + 1, j0, ep);
    float fm[6], fc[6], fq[6];   // fire rows i-1, i, i+1
    load6(fsp, i - 1, j0, fm);
    load6(fsp, i,     j0, fc);
    load6(fsp, i + 1, j0, fq);

    const size_t roff = (size_t)i * W + j0;
    const float4 ws4 = *reinterpret_cast<const float4*>(wsp   + roff);
    const float4 wd4 = *reinterpret_cast<const float4*>(wdp   + roff);
    const float4 hu4 = *reinterpret_cast<const float4*>(hump  + roff);
    const float4 nd4 = *reinterpret_cast<const float4*>(ndvip + roff);
    const float* wsa = reinterpret_cast<const float*>(&ws4);
    const float* wda = reinterpret_cast<const float*>(&wd4);
    const float* hua = reinterpret_cast<const float*>(&hu4);
    const float* nda = reinterpret_cast<const float*>(&nd4);

    float o[4];
#pragma unroll
    for (int k = 0; k < 4; ++k) {
        // Sobel/8 with zero padding
        const float dx = ((em[k+2] - em[k]) + 2.f * (ec[k+2] - ec[k]) +
                          (ep[k+2] - ep[k])) * 0.125f;
        const float dy = ((ep[k]   - em[k]) + 2.f * (ep[k+1] - em[k+1]) +
                          (ep[k+2] - em[k+2])) * 0.125f;
        const float g = sqrtf(dx * dx + dy * dy + 1e-8f);
        // tan(atan(g)) == g  ->  slope_effect = 1 + W_SLOPE*g
        const float slope_eff = 1.f + W_SLOPE * g;
        const float moist = fminf(fmaxf(1.f - 400.f * hua[k], 0.3f), 1.f);
        const float veg   = 0.5f + 0.5f * fminf(fmaxf(nda[k], 0.f), 1.f);
        const float basep = P_BURN * slope_eff * moist * veg;

        // wind_math = mod(270 - wd, 360) degrees; cos(d - w) = c_d*cw + s_d*sw
        const float wrad = fmodf(270.f - wda[k], 360.f) * DEG2RAD;
        float sw, cw;
        __sincosf(wrad, &sw, &cw);

        // max over burning neighbors of cos(d_angle - wind_math)
        float best = -2.f;
        if (fm[k+1] > 0.5f) best = fmaxf(best,  sw);              //  90, (-1, 0)
        if (fm[k+2] > 0.5f) best = fmaxf(best,  C45 * (cw + sw)); //  45, (-1, 1)
        if (fc[k+2] > 0.5f) best = fmaxf(best,  cw);              //   0, ( 0, 1)
        if (fq[k+2] > 0.5f) best = fmaxf(best,  C45 * (cw - sw)); // 315, ( 1, 1)
        if (fq[k+1] > 0.5f) best = fmaxf(best, -sw);              // 270, ( 1, 0)
        if (fq[k]   > 0.5f) best = fmaxf(best, -C45 * (cw + sw)); // 225, ( 1,-1)
        if (fc[k]   > 0.5f) best = fmaxf(best, -cw);              // 180, ( 0,-1)
        if (fm[k]   > 0.5f) best = fmaxf(best,  C45 * (sw - cw)); // 135, (-1,-1)

        float prob = 0.f;
        if (best > -1.5f) {  // at least one burning neighbor
            const float wf = 1.f + W_WIND * best * wsa[k];
            prob = fminf(fmaxf(basep * wf, 0.f), 1.f);
        }
        const float fsc = fc[k + 1];
        o[k] = fmaxf(fsc, (fsc < 0.5f) ? prob : 0.f);
    }

    float4 ov;
    ov.x = o[0]; ov.y = o[1]; ov.z = o[2]; ov.w = o[3];
    *reinterpret_cast<float4*>(out + (size_t)b * plane + roff) = ov;
}

extern "C" void kernel_launch(void* const* d_in, const int* in_sizes, int n_in,
                              void* d_out, int out_size, void* d_ws, size_t ws_size,
                              hipStream_t stream) {
    const float* x = (const float*)d_in[0];
    float* out = (float*)d_out;
    const int B = in_sizes[0] / (CH * H * W);   // 16
    const int total_threads = B * H * (W / 4);  // one thread per 4 pixels
    const int blocks = (total_threads + 255) / 256;
    fire_step<<<blocks, 256, 0, stream>>>(x, out, B);
}